// Round 2
// baseline (112.917 us; speedup 1.0000x reference)
//
#include <hip/hip_runtime.h>
#include <hip/hip_bf16.h>
#include <stdint.h>

#define SQ 8192
#define SK 8192
#define DH 128
#define NIT 32               // iterations
#define L2E 1.4426950408889634f
#define CB 40.0f             // fixed log2-domain softmax offset (R7-proven)

typedef __attribute__((ext_vector_type(8))) _Float16 f16x8;
typedef __attribute__((ext_vector_type(8))) short bf16x8;
typedef __attribute__((ext_vector_type(16))) float f32x16;
typedef __attribute__((ext_vector_type(4))) short s16x4;
typedef __attribute__((ext_vector_type(4))) unsigned int u32x4;

__device__ __forceinline__ short f2h(float f) {
  _Float16 h = (_Float16)f;
  return __builtin_bit_cast(short, h);
}
__device__ __forceinline__ short f2bf(float f) {   // RNE
  uint32_t u = __builtin_bit_cast(uint32_t, f);
  u = (u + 0x7FFFu + ((u >> 16) & 1u)) >> 16;
  return (short)u;
}

__device__ __forceinline__ void gl_lds16(const void* g, void* l) {
  __builtin_amdgcn_global_load_lds(
      (const __attribute__((address_space(1))) void*)g,
      (__attribute__((address_space(3))) void*)l, 16, 0, 0);
}

// ---- prep: blocks [0,256) build K image; blocks [256,512) build V image.
// Kimg[kb][kc][lane][j] = fp16 K[kb*32 + (lane&31)][kc*16 + (lane>>5)*8 + j]
// Vimg[kb][g=ks*4+dt][lane][j] = bf16 V[key][dt*32 + (lane&31)], key axis permuted
//   to S^T C-layout order: key = kb*32 + ks*16 + (lane>>5)*4 + (j&3) + 8*(j>>2).
__global__ __launch_bounds__(256) void prep_kernel(const float* __restrict__ K,
                                                   const float* __restrict__ V,
                                                   short* __restrict__ Kimg,
                                                   short* __restrict__ Vimg) {
  __shared__ short T[32][136];
  const int tid = threadIdx.x;
  if (blockIdx.x < 256) {
    const int kb = blockIdx.x;
#pragma unroll
    for (int i = 0; i < 2; ++i) {
      int ci = i * 256 + tid;            // chunk id, 512 per kb
      int kc = ci >> 6, lane = ci & 63;
      int key = kb * 32 + (lane & 31);
      int k0 = kc * 16 + (lane >> 5) * 8;
      const float* src = K + (size_t)key * DH + k0;
      float4 a = *(const float4*)src;
      float4 b = *(const float4*)(src + 4);
      s16x4 o0, o1;
      o0.x = f2h(a.x); o0.y = f2h(a.y); o0.z = f2h(a.z); o0.w = f2h(a.w);
      o1.x = f2h(b.x); o1.y = f2h(b.y); o1.z = f2h(b.z); o1.w = f2h(b.w);
      s16x4* dst = (s16x4*)(Kimg + (size_t)kb * 4096 + ci * 8);
      dst[0] = o0; dst[1] = o1;
    }
  } else {
    const int kb = blockIdx.x - 256;
#pragma unroll
    for (int i = 0; i < 4; ++i) {
      int fi = i * 256 + tid;            // float4 id in 32x128 tile
      int key = fi >> 5;
      int dc = (fi & 31) * 4;
      float4 v = ((const float4*)V)[(size_t)(kb * 32 + key) * (DH / 4) + (fi & 31)];
      T[key][dc + 0] = f2bf(v.x); T[key][dc + 1] = f2bf(v.y);
      T[key][dc + 2] = f2bf(v.z); T[key][dc + 3] = f2bf(v.w);
    }
    __syncthreads();
#pragma unroll
    for (int i = 0; i < 2; ++i) {
      int ci = i * 256 + tid;            // chunk id, 512 per kb
      int lane = ci & 63;
      int g = ci >> 6;                   // ks*4 + dt
      int dt = g & 3, ks = g >> 2;
      int base = ks * 16 + (lane >> 5) * 4;   // permuted key base
      int d = dt * 32 + (lane & 31);
      s16x4 o0, o1;
      o0.x = T[base + 0][d]; o0.y = T[base + 1][d];
      o0.z = T[base + 2][d]; o0.w = T[base + 3][d];
      o1.x = T[base + 8][d]; o1.y = T[base + 9][d];
      o1.z = T[base + 10][d]; o1.w = T[base + 11][d];
      s16x4* dst = (s16x4*)(Vimg + (size_t)kb * 4096 + ci * 8);
      dst[0] = o0; dst[1] = o1;
    }
  }
}

// ======================= FALLBACK PATH (R0-proven, 110.8 us) ==================
// 32 q-rows/block, grid 256, 8 independent waves (disjoint key stripes), K/V
// frags loaded straight from L2 to registers.
__global__ __launch_bounds__(512, 2) void attn_fallback(const float* __restrict__ Q,
                                                        const short* __restrict__ Kimg,
                                                        const short* __restrict__ Vimg,
                                                        float* __restrict__ out) {
  __shared__ __align__(16) char smem[67584];   // merge only: 4 regions x 32 x 132 fp32
  const int tid = threadIdx.x;
  const int w = tid >> 6;
  const int lane = tid & 63;
  const int half = lane >> 5;
  const int l32 = lane & 31;
  const int qrow0 = blockIdx.x * 32;

  f16x8 qf[8];
  {
    const float* qp = Q + (size_t)(qrow0 + l32) * DH + half * 8;
#pragma unroll
    for (int kc = 0; kc < 8; ++kc) {
      float4 a = *(const float4*)(qp + kc * 16);
      float4 b = *(const float4*)(qp + kc * 16 + 4);
      f16x8 h;
      h[0] = (_Float16)a.x; h[1] = (_Float16)a.y; h[2] = (_Float16)a.z; h[3] = (_Float16)a.w;
      h[4] = (_Float16)b.x; h[5] = (_Float16)b.y; h[6] = (_Float16)b.z; h[7] = (_Float16)b.w;
      qf[kc] = h;
    }
  }

  f32x16 of[4];
#pragma unroll
  for (int dt = 0; dt < 4; ++dt)
#pragma unroll
    for (int c = 0; c < 16; ++c) of[dt][c] = 0.f;
  float l_lane = 0.f;

  f16x8 kf[8];
  bf16x8 vf[8];
  {
    const short* kp = Kimg + (size_t)w * 4096;
    const short* vp = Vimg + (size_t)w * 4096;
#pragma unroll
    for (int kc = 0; kc < 8; ++kc) kf[kc] = *(const f16x8*)(kp + kc * 512 + lane * 8);
#pragma unroll
    for (int g = 0; g < 8; ++g) vf[g] = *(const bf16x8*)(vp + g * 512 + lane * 8);
  }

  for (int t = 0; t < NIT; ++t) {
    f32x16 sacc;
#pragma unroll
    for (int c = 0; c < 16; ++c) sacc[c] = 0.f;
#pragma unroll
    for (int kc = 0; kc < 8; ++kc)
      sacc = __builtin_amdgcn_mfma_f32_32x32x16_f16(kf[kc], qf[kc], sacc, 0, 0, 0);

    if (t + 1 < NIT) {
      const short* kp = Kimg + (size_t)((t + 1) * 8 + w) * 4096;
#pragma unroll
      for (int kc = 0; kc < 8; ++kc) kf[kc] = *(const f16x8*)(kp + kc * 512 + lane * 8);
    }

    u32x4 pav0, pav1;
#pragma unroll
    for (int r = 0; r < 4; ++r) {
      float pA = __builtin_amdgcn_exp2f(fmaf(sacc[2 * r], L2E, -CB));
      float pB = __builtin_amdgcn_exp2f(fmaf(sacc[2 * r + 1], L2E, -CB));
      float pC = __builtin_amdgcn_exp2f(fmaf(sacc[8 + 2 * r], L2E, -CB));
      float pD = __builtin_amdgcn_exp2f(fmaf(sacc[8 + 2 * r + 1], L2E, -CB));
      l_lane += (pA + pB) + (pC + pD);
      uint32_t uA = __builtin_bit_cast(uint32_t, pA); uA += 0x7FFFu + ((uA >> 16) & 1u);
      uint32_t uB = __builtin_bit_cast(uint32_t, pB); uB += 0x7FFFu + ((uB >> 16) & 1u);
      uint32_t uC = __builtin_bit_cast(uint32_t, pC); uC += 0x7FFFu + ((uC >> 16) & 1u);
      uint32_t uD = __builtin_bit_cast(uint32_t, pD); uD += 0x7FFFu + ((uD >> 16) & 1u);
      pav0[r] = __builtin_amdgcn_perm(uB, uA, 0x07060302u);
      pav1[r] = __builtin_amdgcn_perm(uD, uC, 0x07060302u);
    }
    bf16x8 pa0 = __builtin_bit_cast(bf16x8, pav0);
    bf16x8 pa1 = __builtin_bit_cast(bf16x8, pav1);

#pragma unroll
    for (int dt = 0; dt < 4; ++dt) {
      of[dt] = __builtin_amdgcn_mfma_f32_32x32x16_bf16(pa0, vf[dt], of[dt], 0, 0, 0);
      of[dt] = __builtin_amdgcn_mfma_f32_32x32x16_bf16(pa1, vf[4 + dt], of[dt], 0, 0, 0);
    }

    if (t + 1 < NIT) {
      const short* vp = Vimg + (size_t)((t + 1) * 8 + w) * 4096;
#pragma unroll
      for (int g = 0; g < 8; ++g) vf[g] = *(const bf16x8*)(vp + g * 512 + lane * 8);
    }
  }

  float l_tot = l_lane + __shfl_xor(l_lane, 32);

  __syncthreads();
  float* mO = (float*)smem;
  float* R = mO + (w & 3) * 4224;
  if (w < 4) {
#pragma unroll
    for (int c = 0; c < 16; ++c) {
      const int row = (c & 3) + 8 * (c >> 2) + 4 * half;
      float* br = R + row * 132;
#pragma unroll
      for (int dt = 0; dt < 4; ++dt) br[dt * 32 + l32] = of[dt][c];
    }
    if (half == 0) R[l32 * 132 + 128] = l_tot;
  }
  __syncthreads();
  if (w >= 4) {
#pragma unroll
    for (int c = 0; c < 16; ++c) {
      const int row = (c & 3) + 8 * (c >> 2) + 4 * half;
      float* br = R + row * 132;
#pragma unroll
      for (int dt = 0; dt < 4; ++dt) br[dt * 32 + l32] += of[dt][c];
    }
    if (half == 0) R[l32 * 132 + 128] += l_tot;
  }
  __syncthreads();
  {
    const int row = tid >> 4;
    const int cg = tid & 15;
    float den = mO[row * 132 + 128] + mO[4224 + row * 132 + 128] +
                mO[8448 + row * 132 + 128] + mO[12672 + row * 132 + 128];
    float inv = 1.f / den;
    float4 s0 = {0.f, 0.f, 0.f, 0.f}, s1 = {0.f, 0.f, 0.f, 0.f};
#pragma unroll
    for (int rg = 0; rg < 4; ++rg) {
      const float* p = mO + rg * 4224 + row * 132 + cg * 8;
      float4 a = *(const float4*)p;
      float4 b = *(const float4*)(p + 4);
      s0.x += a.x; s0.y += a.y; s0.z += a.z; s0.w += a.w;
      s1.x += b.x; s1.y += b.y; s1.z += b.z; s1.w += b.w;
    }
    s0.x *= inv; s0.y *= inv; s0.z *= inv; s0.w *= inv;
    s1.x *= inv; s1.y *= inv; s1.z *= inv; s1.w *= inv;
    float* op = out + (size_t)(qrow0 + row) * DH + cg * 8;
    *(float4*)op = s0;
    *(float4*)(op + 4) = s1;
  }
}

// ======================= SPLIT PATH (needs 8.45 MB workspace) =================
// 64 q-rows/block, keys split 2-way across blocks -> grid 256. 8 waves =
// (qh in {0,1}) x (ks in {0..3}); per iter the block stages 4 key stripes
// (32 KB K + 32 KB V) into double-buffered LDS via global_load_lds; each
// stripe is read by the two qh waves (2x reuse -> L2 image traffic halved to
// 512 MB). Max-free softmax with fixed CB makes the two key-halves' partials
// additive; block writes unnormalized O + l, combine_kernel divides.
__global__ __launch_bounds__(512, 2) void attn_split(const float* __restrict__ Q,
                                                     const short* __restrict__ Kimg,
                                                     const short* __restrict__ Vimg,
                                                     float* __restrict__ Oa,
                                                     float* __restrict__ Ob,
                                                     float* __restrict__ l0,
                                                     float* __restrict__ l1) {
  // 128 KB: stage[2][32768] shorts; merge region (67584 B) aliases it after loop
  __shared__ __align__(16) char smem[131072];
  short* stg = (short*)smem;
  const int tid = threadIdx.x;
  const int w = tid >> 6;
  const int lane = tid & 63;
  const int half = lane >> 5;
  const int l32 = lane & 31;
  const int qh = w >> 2;               // q-half within block
  const int ks = w & 3;                // key stripe within iter
  const int qb = blockIdx.x >> 1;
  const int kh = blockIdx.x & 1;       // key half: [kh*4096, kh*4096+4096)
  const int qrow0 = qb * 64 + qh * 32;
  const int kb0 = kh * 128;            // first 32-key block of this half

  // Q B-frags fp16: qf[kc][j] = Q[qrow0 + l32][kc*16 + half*8 + j]
  f16x8 qf[8];
  {
    const float* qp = Q + (size_t)(qrow0 + l32) * DH + half * 8;
#pragma unroll
    for (int kc = 0; kc < 8; ++kc) {
      float4 a = *(const float4*)(qp + kc * 16);
      float4 b = *(const float4*)(qp + kc * 16 + 4);
      f16x8 h;
      h[0] = (_Float16)a.x; h[1] = (_Float16)a.y; h[2] = (_Float16)a.z; h[3] = (_Float16)a.w;
      h[4] = (_Float16)b.x; h[5] = (_Float16)b.y; h[6] = (_Float16)b.z; h[7] = (_Float16)b.w;
      qf[kc] = h;
    }
  }

  f32x16 of[4];
#pragma unroll
  for (int dt = 0; dt < 4; ++dt)
#pragma unroll
    for (int c = 0; c < 16; ++c) of[dt][c] = 0.f;
  float l_lane = 0.f;

  // staging: waves 0-3 stage K stripe ks, waves 4-7 stage V stripe ks (8 KB each,
  // linear copy -> LDS layout identical to image block layout). LDS dest is
  // wave-uniform base + lane*16 (global_load_lds requirement); global src per-lane.
  const short* gsrc = (w < 4 ? Kimg : Vimg) + ((size_t)kb0 + ks) * 4096 + lane * 8;
  short* lbase = stg + ((w >= 4) ? 16384 : 0) + ks * 4096;

  auto STAGE = [&](int c, int t) {
    const short* g = gsrc + (size_t)t * 4 * 4096;
    short* l = lbase + c * 32768;
#pragma unroll
    for (int j = 0; j < 8; ++j)
      gl_lds16(g + j * 512, l + j * 512);    // 64 lanes x 16 B = 1 KB per call
  };

  STAGE(0, 0);
  __syncthreads();
  int cur = 0;

  for (int t = 0; t < NIT; ++t) {
    // K frags for this wave's stripe from LDS
    const short* bk = stg + cur * 32768 + ks * 4096 + lane * 8;
    f16x8 kf[8];
#pragma unroll
    for (int kc = 0; kc < 8; ++kc) kf[kc] = *(const f16x8*)(bk + kc * 512);

    // issue next-tile staging early: L2 latency hides under QK+SM+PV
    if (t + 1 < NIT) STAGE(cur ^ 1, t + 1);

    // S^T = K.Q^T (32 keys x 32 q, K=128): C-layout col=q, row=key
    f32x16 sacc;
#pragma unroll
    for (int c = 0; c < 16; ++c) sacc[c] = 0.f;
#pragma unroll
    for (int kc = 0; kc < 8; ++kc)
      sacc = __builtin_amdgcn_mfma_f32_32x32x16_f16(kf[kc], qf[kc], sacc, 0, 0, 0);

    // V frags (independent of sacc -> overlaps softmax)
    const short* bv = stg + cur * 32768 + 16384 + ks * 4096 + lane * 8;
    bf16x8 vf[8];
#pragma unroll
    for (int g2 = 0; g2 < 8; ++g2) vf[g2] = *(const bf16x8*)(bv + g2 * 512);

    // max-free softmax + in-register pack to A-frag (RNE bf16, v_perm pairs)
    u32x4 pav0, pav1;
#pragma unroll
    for (int r = 0; r < 4; ++r) {
      float pA = __builtin_amdgcn_exp2f(fmaf(sacc[2 * r], L2E, -CB));
      float pB = __builtin_amdgcn_exp2f(fmaf(sacc[2 * r + 1], L2E, -CB));
      float pC = __builtin_amdgcn_exp2f(fmaf(sacc[8 + 2 * r], L2E, -CB));
      float pD = __builtin_amdgcn_exp2f(fmaf(sacc[8 + 2 * r + 1], L2E, -CB));
      l_lane += (pA + pB) + (pC + pD);
      uint32_t uA = __builtin_bit_cast(uint32_t, pA); uA += 0x7FFFu + ((uA >> 16) & 1u);
      uint32_t uB = __builtin_bit_cast(uint32_t, pB); uB += 0x7FFFu + ((uB >> 16) & 1u);
      uint32_t uC = __builtin_bit_cast(uint32_t, pC); uC += 0x7FFFu + ((uC >> 16) & 1u);
      uint32_t uD = __builtin_bit_cast(uint32_t, pD); uD += 0x7FFFu + ((uD >> 16) & 1u);
      pav0[r] = __builtin_amdgcn_perm(uB, uA, 0x07060302u);   // [bf(pB)|bf(pA)]
      pav1[r] = __builtin_amdgcn_perm(uD, uC, 0x07060302u);
    }
    bf16x8 pa0 = __builtin_bit_cast(bf16x8, pav0);   // keys 0-15 (permuted order)
    bf16x8 pa1 = __builtin_bit_cast(bf16x8, pav1);   // keys 16-31

    // O += P.V  (V image key-permuted to match pa's key order)
#pragma unroll
    for (int dt = 0; dt < 4; ++dt) {
      of[dt] = __builtin_amdgcn_mfma_f32_32x32x16_bf16(pa0, vf[dt], of[dt], 0, 0, 0);
      of[dt] = __builtin_amdgcn_mfma_f32_32x32x16_bf16(pa1, vf[4 + dt], of[dt], 0, 0, 0);
    }

    __syncthreads();   // drains vmcnt (stage) + lgkmcnt (ds reads), then barrier
    cur ^= 1;
  }

  // combine the two half-lanes' l (each lane's q = l32 appears at half 0 and 1)
  float l_tot = l_lane + __shfl_xor(l_lane, 32);

  // ---- 4-way stripe merge per q-half: 4 LDS regions [32 rows][132 cols] ----
  __syncthreads();
  float* mO = (float*)smem;
  float* R = mO + (qh * 2 + (ks & 1)) * 4224;
  if (ks < 2) {
#pragma unroll
    for (int c = 0; c < 16; ++c) {
      const int row = (c & 3) + 8 * (c >> 2) + 4 * half;   // q-row
      float* br = R + row * 132;
#pragma unroll
      for (int dt = 0; dt < 4; ++dt) br[dt * 32 + l32] = of[dt][c];
    }
    if (half == 0) R[l32 * 132 + 128] = l_tot;
  }
  __syncthreads();
  if (ks >= 2) {
#pragma unroll
    for (int c = 0; c < 16; ++c) {
      const int row = (c & 3) + 8 * (c >> 2) + 4 * half;
      float* br = R + row * 132;
#pragma unroll
      for (int dt = 0; dt < 4; ++dt) br[dt * 32 + l32] += of[dt][c];
    }
    if (half == 0) R[l32 * 132 + 128] += l_tot;
  }
  __syncthreads();
  {
    const int row = tid >> 3;            // 0..63
    const int cg = tid & 7;              // 16-col group
    const int qh2 = row >> 5;
    const int r32 = row & 31;
    const float* Ra = mO + (qh2 * 2 + 0) * 4224 + r32 * 132;
    const float* Rb = mO + (qh2 * 2 + 1) * 4224 + r32 * 132;
    float lp = Ra[128] + Rb[128];        // this block's partial denominator
    float* dst = (kh ? Ob : Oa) + (size_t)(qb * 64 + row) * DH + cg * 16;
#pragma unroll
    for (int k = 0; k < 4; ++k) {
      float4 a = *(const float4*)(Ra + cg * 16 + k * 4);
      float4 b = *(const float4*)(Rb + cg * 16 + k * 4);
      a.x += b.x; a.y += b.y; a.z += b.z; a.w += b.w;
      *(float4*)(dst + k * 4) = a;       // UNNORMALIZED partial
    }
    if (cg == 0) (kh ? l1 : l0)[qb * 64 + row] = lp;
  }
}

// ---- combine: out = (Oa + Ob) / (la + lb), 1M floats, 4/thread ----
__global__ __launch_bounds__(256) void combine_kernel(float* __restrict__ Oa,
                                                      const float* __restrict__ Ob,
                                                      const float* __restrict__ l0,
                                                      const float* __restrict__ l1) {
  const int idx = blockIdx.x * 256 + threadIdx.x;
  const int row = idx >> 5;
  const int c4 = (idx & 31) * 4;
  const float inv = 1.f / (l0[row] + l1[row]);
  float* pa = Oa + (size_t)row * DH + c4;
  const float* pb = Ob + (size_t)row * DH + c4;
  float4 a = *(const float4*)pa;
  float4 b = *(const float4*)pb;
  a.x = (a.x + b.x) * inv; a.y = (a.y + b.y) * inv;
  a.z = (a.z + b.z) * inv; a.w = (a.w + b.w) * inv;
  *(float4*)pa = a;
}

extern "C" void kernel_launch(void* const* d_in, const int* in_sizes, int n_in,
                              void* d_out, int out_size, void* d_ws, size_t ws_size,
                              hipStream_t stream) {
  const float* Q = (const float*)d_in[0];
  const float* K = (const float*)d_in[1];
  const float* V = (const float*)d_in[2];
  float* out = (float*)d_out;
  char* ws = (char*)d_ws;
  short* Kimg = (short*)ws;
  short* Vimg = (short*)(ws + 2097152);
  prep_kernel<<<512, 256, 0, stream>>>(K, V, Kimg, Vimg);
  // split path needs: Kimg 2MB | Vimg 2MB | Ob 4MB | l0 32KB | l1 32KB
  if (ws_size >= (size_t)8454144) {
    float* Ob = (float*)(ws + 4194304);
    float* l0 = (float*)(ws + 8388608);
    float* l1 = l0 + SQ;
    attn_split<<<SQ / 64 * 2, 512, 0, stream>>>(Q, Kimg, Vimg, out, Ob, l0, l1);
    combine_kernel<<<SQ * DH / 4 / 256, 256, 0, stream>>>(out, Ob, l0, l1);
  } else {
    attn_fallback<<<SQ / 32, 512, 0, stream>>>(Q, Kimg, Vimg, out);
  }
}